// Round 8
// baseline (415.362 us; speedup 1.0000x reference)
//
#include <hip/hip_runtime.h>
#include <hip/hip_fp16.h>

typedef _Float16 half8   __attribute__((ext_vector_type(8)));
typedef _Float16 half4_t __attribute__((ext_vector_type(4)));
typedef float    f32x4   __attribute__((ext_vector_type(4)));

#define HDIM  1024
#define BATCH 32
#define TLEN  1024
#define M_TOT (BATCH * TLEN)

#define BM 128
#define BN 128
#define BK 64              // K-tile halves; row = 128 B
#define NIT (HDIM / BK)    // 16

// ---------------- fused prep: We16 convert (0..1023), qproj (1024..2047), zero (2048..2175)
__global__ void prep_k(const float* __restrict__ W, const float* __restrict__ hidden,
                       const float* __restrict__ bias, _Float16* __restrict__ We16,
                       float* __restrict__ q, float* __restrict__ energ) {
    const int bid = blockIdx.x;
    const int t = threadIdx.x;
    if (bid < 1024) {
        int idx = bid * 256 + t;
        int g  = idx >> 8;
        int k4 = idx & 255;
        float4 f = *reinterpret_cast<const float4*>(W + (size_t)g * 2048 + 1024 + k4 * 4);
        half4_t h;
        h[0] = (_Float16)f.x; h[1] = (_Float16)f.y; h[2] = (_Float16)f.z; h[3] = (_Float16)f.w;
        *reinterpret_cast<half4_t*>(We16 + (size_t)idx * 4) = h;
    } else if (bid < 2048) {
        int g = bid - 1024;
        int wave = t >> 6, lane = t & 63;
        float acc[BATCH];
#pragma unroll
        for (int b = 0; b < BATCH; b++) acc[b] = 0.f;
        const float* wr = W + (size_t)g * 2048;
        for (int h = t; h < HDIM; h += 256) {
            float w = wr[h];
#pragma unroll
            for (int b = 0; b < BATCH; b++) acc[b] = fmaf(w, hidden[b * HDIM + h], acc[b]);
        }
        __shared__ float sm[4 * BATCH];
#pragma unroll
        for (int b = 0; b < BATCH; b++) {
            float s = acc[b];
#pragma unroll
            for (int off = 32; off >= 1; off >>= 1) s += __shfl_xor(s, off);
            if (lane == 0) sm[wave * BATCH + b] = s;
        }
        __syncthreads();
        if (t < BATCH) {
            float s = sm[t] + sm[BATCH + t] + sm[2 * BATCH + t] + sm[3 * BATCH + t];
            q[t * HDIM + g] = s + bias[g];
        }
    } else {
        energ[(bid - 2048) * 256 + t] = 0.f;
    }
}

__device__ __forceinline__ void async16(const void* g, void* l) {
    __builtin_amdgcn_global_load_lds(
        (const __attribute__((address_space(1))) void*)g,
        (__attribute__((address_space(3))) void*)l, 16, 0, 0);
}

// ---------------- fused GEMM: A = enc fp32 (in-kernel convert), B = We16 via global_load_lds
// R4 skeleton: BK=64, XOR swizzle c^(r&7) (measured 0 conflicts), issue-early, 2 barriers/iter.
// 1D grid 2048. xcd=id&7; each XCD owns 32 m-stripes; 8 n-blocks of a stripe dispatch-adjacent.
__global__ __launch_bounds__(256)
void attn_gemm_fused_k(const float* __restrict__ enc,
                       const _Float16* __restrict__ We16,
                       const float* __restrict__ q, const float* __restrict__ v,
                       float* __restrict__ energies) {
    __shared__ _Float16 As[BM * BK];   // 16 KB, rows 128 B, chunk c of row r at c^(r&7)
    __shared__ _Float16 Bs[BN * BK];   // 16 KB, same layout (filled by global_load_lds)

    const int tid  = threadIdx.x;
    const int id   = blockIdx.x;
    const int xcd  = id & 7;
    const int w    = id >> 3;
    const int m0   = (xcd * 32 + (w >> 3)) * BM;
    const int n0   = (w & 7) * BN;
    const int wave = tid >> 6;
    const int lane = tid & 63;
    const int quad = lane >> 4;
    const int l16  = lane & 15;
    const int wm   = (wave & 1) * 64;
    const int wn   = (wave >> 1) * 64;

    f32x4 acc[4][4];
#pragma unroll
    for (int i = 0; i < 4; i++)
#pragma unroll
        for (int j = 0; j < 4; j++) acc[i][j] = {0.f, 0.f, 0.f, 0.f};

    // ---- A staging (fp32 -> fp16 via registers): thread t -> row t>>1, half-row t&1
    const int arow = tid >> 1;
    const int ahalf = tid & 1;                       // source chunks 4*ahalf .. 4*ahalf+3
    const float* gA = enc + (size_t)(m0 + arow) * HDIM + ahalf * 32;
    const int aswz = arow & 7;
    const int abase = arow * BK;

    // ---- B staging via global_load_lds (R4 map): issue ii rows wave*32+ii*8+(lane>>3)
    const int bsrow = wave * 32 + (lane >> 3);
    const int bscol = ((lane & 7) ^ (lane >> 3)) * 8;   // fetched chunk pre-swizzled
    const _Float16* gB = We16 + (size_t)(n0 + bsrow) * HDIM + bscol;
    _Float16* lB = Bs + wave * 2048;                    // + ii*512 halves
    const size_t bistep = (size_t)8 * HDIM;

    // ---- prologue: tile 0
#pragma unroll
    for (int ii = 0; ii < 4; ii++) async16(gB + ii * bistep, lB + ii * 512);
    {
        float4 fl[8];
#pragma unroll
        for (int j = 0; j < 8; j++) fl[j] = *reinterpret_cast<const float4*>(gA + j * 4);
#pragma unroll
        for (int j = 0; j < 4; j++) {
            half8 h;
            h[0] = (_Float16)fl[2*j].x;   h[1] = (_Float16)fl[2*j].y;
            h[2] = (_Float16)fl[2*j].z;   h[3] = (_Float16)fl[2*j].w;
            h[4] = (_Float16)fl[2*j+1].x; h[5] = (_Float16)fl[2*j+1].y;
            h[6] = (_Float16)fl[2*j+1].z; h[7] = (_Float16)fl[2*j+1].w;
            *reinterpret_cast<half8*>(&As[abase + (((4*ahalf + j) ^ aswz) * 8)]) = h;
        }
    }
    __syncthreads();   // drains vmcnt (B tile 0) + lgkm (A writes)

    // frag read offsets: row r, chunk c=s*4+quad stored at c^(r&7); r&7 == l16&7 here
    int aoff[2][4], boff[2][4];
#pragma unroll
    for (int s = 0; s < 2; s++)
#pragma unroll
        for (int i = 0; i < 4; i++) {
            int ra = wm + i * 16 + l16;
            int rb = wn + i * 16 + l16;
            aoff[s][i] = ra * BK + (((s * 4 + quad) ^ (l16 & 7)) * 8);
            boff[s][i] = rb * BK + (((s * 4 + quad) ^ (l16 & 7)) * 8);
        }

    for (int it = 0; it < NIT; it++) {
        // read ALL frags for this tile
        half8 af[2][4], bf[2][4];
#pragma unroll
        for (int s = 0; s < 2; s++)
#pragma unroll
            for (int i = 0; i < 4; i++) {
                af[s][i] = *reinterpret_cast<const half8*>(&As[aoff[s][i]]);
                bf[s][i] = *reinterpret_cast<const half8*>(&Bs[boff[s][i]]);
            }
        __syncthreads();   // all waves done reading LDS

        float4 fl[8];
        const bool more = (it + 1 < NIT);
        if (more) {
            const int k = (it + 1) * BK;
#pragma unroll
            for (int ii = 0; ii < 4; ii++) async16(gB + k + ii * bistep, lB + ii * 512);
#pragma unroll
            for (int j = 0; j < 8; j++) fl[j] = *reinterpret_cast<const float4*>(gA + k + j * 4);
        }

#pragma unroll
        for (int s = 0; s < 2; s++)
#pragma unroll
            for (int mi = 0; mi < 4; mi++)
#pragma unroll
                for (int ni = 0; ni < 4; ni++)
                    acc[mi][ni] = __builtin_amdgcn_mfma_f32_16x16x32_f16(af[s][mi], bf[s][ni], acc[mi][ni], 0, 0, 0);

        if (more) {
#pragma unroll
            for (int j = 0; j < 4; j++) {
                half8 h;
                h[0] = (_Float16)fl[2*j].x;   h[1] = (_Float16)fl[2*j].y;
                h[2] = (_Float16)fl[2*j].z;   h[3] = (_Float16)fl[2*j].w;
                h[4] = (_Float16)fl[2*j+1].x; h[5] = (_Float16)fl[2*j+1].y;
                h[6] = (_Float16)fl[2*j+1].z; h[7] = (_Float16)fl[2*j+1].w;
                *reinterpret_cast<half8*>(&As[abase + (((4*ahalf + j) ^ aswz) * 8)]) = h;
            }
        }
        __syncthreads();   // drains vmcnt (B DMA) + lgkm (A writes)
    }

    // ---- epilogue: C/D col = l16, row = quad*4 + r
    const int bidx = m0 >> 10;
    float qv[4], vv[4];
#pragma unroll
    for (int ni = 0; ni < 4; ni++) {
        int g = n0 + wn + ni * 16 + l16;
        qv[ni] = q[bidx * HDIM + g];
        vv[ni] = v[g];
    }
#pragma unroll
    for (int mi = 0; mi < 4; mi++) {
#pragma unroll
        for (int r = 0; r < 4; r++) {
            int row = wm + mi * 16 + quad * 4 + r;
            float s = 0.f;
#pragma unroll
            for (int ni = 0; ni < 4; ni++) {
                float pre = acc[mi][ni][r] + qv[ni];
                float e = __expf(2.f * pre);
                float th = 1.f - 2.f / (e + 1.f);
                s = fmaf(th, vv[ni], s);
            }
            s += __shfl_xor(s, 1);
            s += __shfl_xor(s, 2);
            s += __shfl_xor(s, 4);
            s += __shfl_xor(s, 8);
            if (l16 == 0) atomicAdd(&energies[m0 + row], s);
        }
    }
}

// ---------------- softmax over t per batch row ----------------
__global__ void softmax_k(const float* __restrict__ energies, float* __restrict__ out) {
    int b = blockIdx.x;
    int t = threadIdx.x;
    int wave = t >> 6, lane = t & 63;
    __shared__ float smax[4], ssum[4];
    float e[4];
#pragma unroll
    for (int i = 0; i < 4; i++) e[i] = energies[b * TLEN + t + i * 256];
    float m = fmaxf(fmaxf(e[0], e[1]), fmaxf(e[2], e[3]));
#pragma unroll
    for (int off = 32; off >= 1; off >>= 1) m = fmaxf(m, __shfl_xor(m, off));
    if (lane == 0) smax[wave] = m;
    __syncthreads();
    float M = fmaxf(fmaxf(smax[0], smax[1]), fmaxf(smax[2], smax[3]));
    float x[4]; float s = 0.f;
#pragma unroll
    for (int i = 0; i < 4; i++) { x[i] = __expf(e[i] - M); s += x[i]; }
#pragma unroll
    for (int off = 32; off >= 1; off >>= 1) s += __shfl_xor(s, off);
    if (lane == 0) ssum[wave] = s;
    __syncthreads();
    float S = ssum[0] + ssum[1] + ssum[2] + ssum[3];
    float inv = 1.f / S;
#pragma unroll
    for (int i = 0; i < 4; i++) out[b * TLEN + t + i * 256] = x[i] * inv;
}

extern "C" void kernel_launch(void* const* d_in, const int* in_sizes, int n_in,
                              void* d_out, int out_size, void* d_ws, size_t ws_size,
                              hipStream_t stream) {
    const float* hidden = (const float*)d_in[0];   // (1, 32, 1024) fp32
    const float* enc    = (const float*)d_in[1];   // (32, 1024, 1024) fp32
    const float* W      = (const float*)d_in[2];   // (1024, 2048) fp32
    const float* bias   = (const float*)d_in[3];   // (1024,) fp32
    const float* v      = (const float*)d_in[4];   // (1024,) fp32
    float* out = (float*)d_out;                    // (32, 1, 1024) fp32

    char* ws = (char*)d_ws;
    float*    q     = (float*)ws;                  // 128 KB
    float*    energ = (float*)(ws + 131072);       // 128 KB
    _Float16* We16  = (_Float16*)(ws + 262144);    // 2 MB

    // prep: blocks 0..1023 we_convert, 1024..2047 qproj, 2048..2175 zero energies
    prep_k<<<dim3(2176), 256, 0, stream>>>(W, hidden, bias, We16, q, energ);
    attn_gemm_fused_k<<<dim3(2048), 256, 0, stream>>>(enc, We16, q, v, energ);
    softmax_k<<<dim3(BATCH), 256, 0, stream>>>(energ, out);
}